// Round 12
// baseline (585.645 us; speedup 1.0000x reference)
//
#include <hip/hip_runtime.h>
#include <hip/hip_bf16.h>
#include <stdint.h>

#define TOKENS 8192
#define DDIM 1024
#define HDIM 4096
#define NEXP 8
#define MAXENT 16384
#define MAXTILES 72

typedef __attribute__((ext_vector_type(4))) float f32x4;
typedef __attribute__((ext_vector_type(8))) short bf16x8;
typedef __attribute__((ext_vector_type(4))) int i32x4;

__device__ __forceinline__ unsigned short f2bf(float f) {
  __hip_bfloat16 h = __float2bfloat16(f);
  return __builtin_bit_cast(unsigned short, h);
}

__device__ __forceinline__ void gload16(const void* g, void* l) {
  __builtin_amdgcn_global_load_lds(
      (const __attribute__((address_space(1))) unsigned int*)g,
      (__attribute__((address_space(3))) unsigned int*)l, 16, 0, 0);
}

__device__ __forceinline__ void bar0() {
  asm volatile("" ::: "memory");
  __builtin_amdgcn_s_barrier();
  asm volatile("" ::: "memory");
}

#define VMWAIT(N) asm volatile("s_waitcnt vmcnt(" #N ")" ::: "memory")

// ---------------- prep ----------------

__global__ void moe_count(const int* __restrict__ idx, int* __restrict__ meta) {
  int t = blockIdx.x * 256 + threadIdx.x;
  if (t >= TOKENS) return;
  int e0 = idx[2 * t], e1 = idx[2 * t + 1];
  atomicAdd(&meta[e0], 1);
  if (e1 != e0) atomicAdd(&meta[e1], 1);
}

__global__ void moe_scan(int* __restrict__ meta) {
  if (threadIdx.x != 0 || blockIdx.x != 0) return;
  int s = 0;
  for (int e = 0; e < NEXP; ++e) { meta[16 + e] = s; meta[32 + e] = s; s += meta[e]; }
  meta[16 + NEXP] = s;
  int nt = 0;
  for (int e = 0; e < NEXP; ++e) {
    int m = (meta[e] + 255) >> 8;  // 256-entry tiles
    for (int t = 0; t < m; ++t) meta[64 + nt++] = e | (t << 8);
  }
  meta[48] = nt;
}

__global__ void moe_scatter(const int* __restrict__ idx, const float* __restrict__ ew,
                            int* __restrict__ meta, int* __restrict__ etok,
                            float* __restrict__ ewgt) {
  int t = blockIdx.x * 256 + threadIdx.x;
  if (t >= TOKENS) return;
  int e0 = idx[2 * t], e1 = idx[2 * t + 1];
  float a = ew[2 * t], b = ew[2 * t + 1];
  if (e0 == e1) {
    int p = atomicAdd(&meta[32 + e0], 1);
    etok[p] = t; ewgt[p] = a + b;
  } else {
    int p = atomicAdd(&meta[32 + e0], 1);
    etok[p] = t; ewgt[p] = a;
    int q = atomicAdd(&meta[32 + e1], 1);
    etok[q] = t; ewgt[q] = b;
  }
}

// ---- gather x -> A-pretile pages: [page256][kt32][chunk16][lane64][8] bf16 ----
// ent = ent0 + chunk*16 + (lane&15); k = kt*32 + (lane>>4)*8 + i

__global__ __launch_bounds__(256) void gather_pre(const float* __restrict__ x,
                                                  const int* __restrict__ etok,
                                                  const int* __restrict__ meta,
                                                  unsigned short* __restrict__ xgp) {
  int ntiles = meta[48];
  int page = blockIdx.x, kt = blockIdx.y;
  if (page >= ntiles) return;
  int te = meta[64 + page];
  int e = te & 255, mt = te >> 8;
  int ent0 = meta[16 + e] + mt * 256, lim = meta[16 + e + 1];
  int tid = threadIdx.x;
#pragma unroll
  for (int it = 0; it < 4; ++it) {
    int u = it * 256 + tid;
    int chunk = u >> 6, lane = u & 63;
    int ent = ent0 + chunk * 16 + (lane & 15);
    if (ent > lim - 1) ent = lim - 1;
    int tok = etok[ent];
    const float4* s = (const float4*)(x + (size_t)tok * DDIM + kt * 32 + ((lane >> 4) << 3));
    float4 a = s[0], b = s[1];
    union { unsigned short h[8]; i32x4 v; } o;
    o.h[0] = f2bf(a.x); o.h[1] = f2bf(a.y); o.h[2] = f2bf(a.z); o.h[3] = f2bf(a.w);
    o.h[4] = f2bf(b.x); o.h[5] = f2bf(b.y); o.h[6] = f2bf(b.z); o.h[7] = f2bf(b.w);
    ((i32x4*)xgp)[(size_t)(page * 32 + kt) * 1024 + u] = o.v;
  }
}

// ---- weights -> B-pretile: [e][nt256][kt32][chunk16][lane64][8] bf16 ----
__global__ __launch_bounds__(256) void pretile_w(const float* __restrict__ src,
                                                 unsigned short* __restrict__ dst,
                                                 int Kdim, int Ndim) {
  __shared__ unsigned short t16[64][266];
  int NB = Ndim >> 8, KB = Kdim >> 6;
  int bid = blockIdx.x;
  int kblk = bid % KB; int rest = bid / KB;
  int nblk = rest % NB; int e = rest / NB;
  const float* s = src + ((size_t)e * Kdim + ((size_t)kblk << 6)) * Ndim + ((size_t)nblk << 8);
  int tid = threadIdx.x;
  int cp = tid & 127, rh = tid >> 7;
#pragma unroll
  for (int rr = 0; rr < 32; ++rr) {
    int r = rh * 32 + rr;
    float2 v = *(const float2*)(s + (size_t)r * Ndim + 2 * cp);
    unsigned int pk = (unsigned int)f2bf(v.x) | ((unsigned int)f2bf(v.y) << 16);
    *(unsigned int*)&t16[r][2 * cp] = pk;
  }
  __syncthreads();
  int KT32 = Kdim >> 5;
#pragma unroll
  for (int it = 0; it < 8; ++it) {
    int u = it * 256 + tid;
    int kt2 = u >> 10, rem = u & 1023;
    int chunk = rem >> 6, lane = rem & 63;
    int nl = chunk * 16 + (lane & 15);
    int kl = kt2 * 32 + ((lane >> 4) << 3);
    union { unsigned short h[8]; i32x4 v; } o;
#pragma unroll
    for (int i = 0; i < 8; ++i) o.h[i] = t16[kl + i][nl];
    size_t idx = (((size_t)e * NB + nblk) * KT32 + kblk * 2 + kt2) * 1024 + rem;
    ((i32x4*)dst)[idx] = o.v;
  }
}

// ---- GEMM: 256x128 tile, BK=32, 8 waves (4M x 2N, wave tile 64x64, acc=64 regs),
//      48 KB LDS (2+2 slots), 4 waves/SIMD + 2 blocks/CU, snake XCD mapping ----

template <int MODE>
__global__ __launch_bounds__(512, 4) void moe_gemm(
    const unsigned short* __restrict__ Apre,  // pages [*][AKT][16KB]
    const unsigned short* __restrict__ Bpre,  // [e][nt256][kt32][16KB? grouped 32KB/kt64] fragment-major
    const float* __restrict__ bias,
    const int* __restrict__ meta,
    const int* __restrict__ etok,
    const float* __restrict__ ewgt,
    unsigned short* __restrict__ Hbuf,
    float* __restrict__ Out,
    int AKT, int BtNT256, int BtKT32, int ntg0, int kt0B,
    int nk, int biasOff, int bstr, int sIsZero, int KT_H) {
  const int* offsets = meta + 16;
  int ntiles = meta[48];
  int NX = gridDim.x;
  int lid = blockIdx.x + NX * blockIdx.y;
  int Ntot = NX * ntiles;
  if (lid >= Ntot) return;
  int q = Ntot >> 3, r = Ntot & 7;
  int xcd = lid & 7, pos = lid >> 3;
  int nlid = (xcd < r ? xcd * (q + 1) : r * (q + 1) + (xcd - r) * q) + pos;
  // nt-fastest snake within each XCD chunk: A-page L2-resident per XCD
  int mti = nlid / NX;
  int rawnt = nlid - mti * NX;
  int nt = (mti & 1) ? (NX - 1 - rawnt) : rawnt;
  int te = meta[64 + mti];
  int e = te & 255, mt = te >> 8;
  int off = offsets[e], cnt = offsets[e + 1] - off;

  // A: 2 slots x 16 KiB at [0,32K). B: 2 slots x 8 KiB at [32K,48K).
  __shared__ __align__(128) char lds[49152];

  int tid = threadIdx.x, lane = tid & 63, wid = tid >> 6;
  int wr = wid >> 1, wc = wid & 1;
  int fr = lane & 15, fu = lane >> 4;

  const char* srcA = (const char*)Apre + ((size_t)mti * AKT << 14) + (tid << 4);
  int ntg = ntg0 + nt;  // global 128-col tile index
  const char* srcB = (const char*)Bpre +
      ((((size_t)e * BtNT256 + (ntg >> 1)) * BtKT32 + kt0B) << 14) +
      ((size_t)(ntg & 1) << 13) + (tid << 4);

#define STAGE(Tn) do { \
    char* _a = lds + (((Tn) & 1) << 14) + (tid << 4); \
    const char* _sa = srcA + ((size_t)(Tn) << 14); \
    gload16(_sa, _a); gload16(_sa + 8192, _a + 8192); \
    gload16(srcB + ((size_t)(Tn) << 14), lds + 32768 + (((Tn) & 1) << 13) + (tid << 4)); \
  } while (0)

  f32x4 acc[4][4];
#pragma unroll
  for (int m = 0; m < 4; ++m)
#pragma unroll
    for (int n = 0; n < 4; ++n) acc[m][n] = (f32x4){0.f, 0.f, 0.f, 0.f};

  STAGE(0);
  VMWAIT(0);
  bar0();

  for (int kt = 0; kt < nk; ++kt) {
    const char* pa = lds + ((kt & 1) << 14) + ((wr * 4) << 10) + (lane << 4);
    const char* pb = lds + 32768 + ((kt & 1) << 13) + ((wc * 4) << 10) + (lane << 4);
    bf16x8 af[4], bg[4];
#pragma unroll
    for (int m = 0; m < 4; ++m) af[m] = *(const bf16x8*)(pa + m * 1024);
#pragma unroll
    for (int n = 0; n < 4; ++n) bg[n] = *(const bf16x8*)(pb + n * 1024);
    if (kt + 1 < nk) STAGE(kt + 1);
    __builtin_amdgcn_s_setprio(1);
#pragma unroll
    for (int m = 0; m < 4; ++m)
#pragma unroll
      for (int n = 0; n < 4; ++n)
        acc[m][n] = __builtin_amdgcn_mfma_f32_16x16x32_bf16(af[m], bg[n], acc[m][n], 0, 0, 0);
    __builtin_amdgcn_s_setprio(0);
    VMWAIT(0);
    bar0();
  }
#undef STAGE

  if (MODE == 0) {
    // write hbuf page in A-pretile layout (page covers full HC width)
    unsigned short* page = Hbuf + (size_t)mti * KT_H * 8192;
#pragma unroll
    for (int m = 0; m < 4; ++m) {
#pragma unroll
      for (int r = 0; r < 4; ++r) {
        int row = wr * 64 + m * 16 + fu * 4 + r;
        int gm = mt * 256 + row;
        if (gm < cnt) {
#pragma unroll
          for (int n = 0; n < 4; ++n) {
            int lc = nt * 128 + wc * 64 + n * 16 + fr;
            float v = acc[m][n][r] + bias[e * bstr + biasOff + lc];
            v = v / (1.f + __expf(-v));
            int kt = lc >> 5;
            int idx = (((kt * 16 + (row >> 4)) << 9) +
                       (((row & 15) + (((lc >> 3) & 3) << 4)) << 3) + (lc & 7));
            page[idx] = f2bf(v);
          }
        }
      }
    }
  } else {
#pragma unroll
    for (int m = 0; m < 4; ++m) {
#pragma unroll
      for (int r = 0; r < 4; ++r) {
        int row = wr * 64 + m * 16 + fu * 4 + r;
        int gm = mt * 256 + row;
        if (gm < cnt) {
          int ent = off + gm;
          int tok = etok[ent];
          float wgt = ewgt[ent];
#pragma unroll
          for (int n = 0; n < 4; ++n) {
            int col = nt * 128 + wc * 64 + n * 16 + fr;
            float v = acc[m][n][r];
            if (sIsZero) v += bias[e * bstr + col];
            atomicAdd(Out + (size_t)tok * DDIM + col, v * wgt);
          }
        }
      }
    }
  }
}

// ---------------- host launch ----------------

extern "C" void kernel_launch(void* const* d_in, const int* in_sizes, int n_in,
                              void* d_out, int out_size, void* d_ws, size_t ws_size,
                              hipStream_t stream) {
  (void)in_sizes; (void)n_in;
  const float* x = (const float*)d_in[0];
  const int* eidx = (const int*)d_in[1];
  const float* ew = (const float*)d_in[2];
  const float* w1 = (const float*)d_in[3];
  const float* b1 = (const float*)d_in[4];
  const float* w2 = (const float*)d_in[5];
  const float* b2 = (const float*)d_in[6];
  float* out = (float*)d_out;

  char* w = (char*)d_ws;
  size_t o_meta = 0;
  size_t o_etok = 4096;
  size_t o_ewgt = o_etok + (size_t)MAXENT * 4;
  size_t o_xgp  = o_ewgt + (size_t)MAXENT * 4;
  size_t o_w1t  = o_xgp + (size_t)MAXTILES * 32 * 16384;   // 36 MB
  size_t o_w2t  = o_w1t + (size_t)NEXP * DDIM * HDIM * 2;  // +64 MB
  size_t o_h    = o_w2t + (size_t)NEXP * DDIM * HDIM * 2;  // +64 MB

  int S = 1;
  while (S < 16) {
    size_t need = o_h + (size_t)MAXTILES * ((HDIM / S) >> 5) * 16384;
    if (need <= ws_size) break;
    S *= 2;
  }
  int HC = HDIM / S;
  int KT_H = HC >> 5;

  int* meta = (int*)(w + o_meta);
  int* etok = (int*)(w + o_etok);
  float* ewgt = (float*)(w + o_ewgt);
  unsigned short* xgp = (unsigned short*)(w + o_xgp);
  unsigned short* w1t = (unsigned short*)(w + o_w1t);
  unsigned short* w2t = (unsigned short*)(w + o_w2t);
  unsigned short* hbuf = (unsigned short*)(w + o_h);

  hipMemsetAsync(w + o_meta, 0, 4096, stream);
  hipMemsetAsync(d_out, 0, (size_t)out_size * 4, stream);

  moe_count<<<TOKENS / 256, 256, 0, stream>>>(eidx, meta);
  moe_scan<<<1, 64, 0, stream>>>(meta);
  moe_scatter<<<TOKENS / 256, 256, 0, stream>>>(eidx, ew, meta, etok, ewgt);
  gather_pre<<<dim3(MAXTILES, DDIM / 32), 256, 0, stream>>>(x, etok, meta, xgp);
  pretile_w<<<NEXP * (HDIM >> 8) * (DDIM >> 6), 256, 0, stream>>>(w1, w1t, DDIM, HDIM);
  pretile_w<<<NEXP * (DDIM >> 8) * (HDIM >> 6), 256, 0, stream>>>(w2, w2t, HDIM, DDIM);

  for (int s = 0; s < S; ++s) {
    // MODE 0: xgp @ w1t -> silu -> hbuf pages
    moe_gemm<0><<<dim3(HC / 128, MAXTILES), 512, 0, stream>>>(
        xgp, w1t, b1, meta, etok, ewgt, hbuf, nullptr,
        /*AKT*/ DDIM >> 5, /*BtNT256*/ HDIM >> 8, /*BtKT32*/ DDIM >> 5,
        /*ntg0*/ (s * HC) >> 7, /*kt0B*/ 0,
        /*nk*/ DDIM >> 5, /*biasOff*/ s * HC, /*bstr*/ HDIM, 1, KT_H);
    // MODE 1: hbuf @ w2t -> atomic out
    moe_gemm<1><<<dim3(DDIM / 128, MAXTILES), 512, 0, stream>>>(
        hbuf, w2t, b2, meta, etok, ewgt, nullptr, out,
        /*AKT*/ KT_H, /*BtNT256*/ DDIM >> 8, /*BtKT32*/ HDIM >> 5,
        /*ntg0*/ 0, /*kt0B*/ (s * HC) >> 5,
        /*nk*/ KT_H, /*biasOff*/ 0, /*bstr*/ DDIM, (s == 0) ? 1 : 0, KT_H);
  }
}

// Round 13
// 454.597 us; speedup vs baseline: 1.2883x; 1.2883x over previous
//
#include <hip/hip_runtime.h>
#include <hip/hip_bf16.h>
#include <stdint.h>

#define TOKENS 8192
#define DDIM 1024
#define HDIM 4096
#define NEXP 8
#define MAXENT 16384
#define MAXTILES 72

typedef __attribute__((ext_vector_type(4))) float f32x4;
typedef __attribute__((ext_vector_type(8))) short bf16x8;
typedef __attribute__((ext_vector_type(4))) int i32x4;

__device__ __forceinline__ unsigned short f2bf(float f) {
  __hip_bfloat16 h = __float2bfloat16(f);
  return __builtin_bit_cast(unsigned short, h);
}

__device__ __forceinline__ void gload16(const void* g, void* l) {
  __builtin_amdgcn_global_load_lds(
      (const __attribute__((address_space(1))) unsigned int*)g,
      (__attribute__((address_space(3))) unsigned int*)l, 16, 0, 0);
}

__device__ __forceinline__ void bar() {
  asm volatile("" ::: "memory");
  __builtin_amdgcn_sched_barrier(0);
  __builtin_amdgcn_s_barrier();
  __builtin_amdgcn_sched_barrier(0);
  asm volatile("" ::: "memory");
}

#define VMWAIT(N) asm volatile("s_waitcnt vmcnt(" #N ")" ::: "memory")

// ---------------- prep: one workgroup does count + scan + tile list + scatter ----------------

__global__ __launch_bounds__(1024) void prep_all(const int* __restrict__ idx,
                                                 const float* __restrict__ ew,
                                                 int* __restrict__ meta,
                                                 int* __restrict__ etok,
                                                 float* __restrict__ ewgt) {
  __shared__ int cnt[NEXP];
  int tid = threadIdx.x;
  if (tid < NEXP) cnt[tid] = 0;
  __syncthreads();
  for (int t = tid; t < TOKENS; t += 1024) {
    int e0 = idx[2 * t], e1 = idx[2 * t + 1];
    atomicAdd(&cnt[e0], 1);
    if (e1 != e0) atomicAdd(&cnt[e1], 1);
  }
  __syncthreads();
  if (tid == 0) {
    int s = 0, nt = 0;
    int base[NEXP];
    for (int e = 0; e < NEXP; ++e) {
      base[e] = s;
      meta[16 + e] = s;
      s += cnt[e];
    }
    meta[16 + NEXP] = s;
    for (int e = 0; e < NEXP; ++e) {
      int m = (cnt[e] + 255) >> 8;
      for (int t2 = 0; t2 < m; ++t2) meta[64 + nt++] = e | (t2 << 8);
    }
    meta[48] = nt;
    for (int e = 0; e < NEXP; ++e) cnt[e] = base[e];  // reuse as scatter cursors
  }
  __syncthreads();
  for (int t = tid; t < TOKENS; t += 1024) {
    int e0 = idx[2 * t], e1 = idx[2 * t + 1];
    float a = ew[2 * t], b = ew[2 * t + 1];
    if (e0 == e1) {
      int p = atomicAdd(&cnt[e0], 1);
      etok[p] = t; ewgt[p] = a + b;
    } else {
      int p = atomicAdd(&cnt[e0], 1);
      etok[p] = t; ewgt[p] = a;
      int q = atomicAdd(&cnt[e1], 1);
      etok[q] = t; ewgt[q] = b;
    }
  }
}

// ---------------- x -> bf16 (coalesced) ----------------

__global__ void cvt_x_bf16(const float* __restrict__ src, unsigned short* __restrict__ dst, int n8) {
  int i = blockIdx.x * 256 + threadIdx.x;
  if (i >= n8) return;
  const float4* s4 = (const float4*)src;
  float4 a = s4[2 * i], b = s4[2 * i + 1];
  union { unsigned short h[8]; i32x4 v; } o;
  o.h[0] = f2bf(a.x); o.h[1] = f2bf(a.y); o.h[2] = f2bf(a.z); o.h[3] = f2bf(a.w);
  o.h[4] = f2bf(b.x); o.h[5] = f2bf(b.y); o.h[6] = f2bf(b.z); o.h[7] = f2bf(b.w);
  ((i32x4*)dst)[i] = o.v;
}

// ---- both weights -> fragment-major pretile in ONE launch ----
// layout: [e][ntile256][ktile64][chunk(0..31)][lane(0..63)][8] bf16
// chunk = nf*2 + ks ; n = ntile*256 + nf*16 + (lane&15)
//                     k = ktile*64 + ks*32 + (lane>>4)*8 + i
__global__ __launch_bounds__(256) void pretile_both(const float* __restrict__ w1,
                                                    const float* __restrict__ w2,
                                                    unsigned short* __restrict__ d1,
                                                    unsigned short* __restrict__ d2) {
  __shared__ unsigned short t16[64][266];
  const int nb1 = NEXP * (HDIM >> 8) * (DDIM >> 6);
  int bid = blockIdx.x;
  const float* src; unsigned short* dst; int Kdim, Ndim;
  if (bid < nb1) { src = w1; dst = d1; Kdim = DDIM; Ndim = HDIM; }
  else { bid -= nb1; src = w2; dst = d2; Kdim = HDIM; Ndim = DDIM; }
  int KT = Kdim >> 6, NT = Ndim >> 8;
  int ktile = bid % KT; int rest = bid / KT;
  int ntile = rest % NT; int e = rest / NT;
  const float* s = src + ((size_t)e * Kdim + ((size_t)ktile << 6)) * Ndim + ((size_t)ntile << 8);
  int tid = threadIdx.x;
  int cp = tid & 127, rh = tid >> 7;
#pragma unroll
  for (int rr = 0; rr < 32; ++rr) {
    int r = rh * 32 + rr;
    float2 v = *(const float2*)(s + (size_t)r * Ndim + 2 * cp);
    unsigned int pk = (unsigned int)f2bf(v.x) | ((unsigned int)f2bf(v.y) << 16);
    *(unsigned int*)&t16[r][2 * cp] = pk;
  }
  __syncthreads();
  size_t obase = (((size_t)e * NT + ntile) * KT + ktile) << 11;
#pragma unroll
  for (int it = 0; it < 8; ++it) {
    int u = it * 256 + tid;
    int chunk = u >> 6, lane = u & 63;
    int nl = ((chunk >> 1) << 4) + (lane & 15);
    int kl = ((chunk & 1) << 5) + ((lane >> 4) << 3);
    union { unsigned short h[8]; i32x4 v; } o;
#pragma unroll
    for (int i = 0; i < 8; ++i) o.h[i] = t16[kl + i][nl];
    ((i32x4*)dst)[obase + u] = o.v;
  }
}

// ---- GEMM: 256x256, BK=64, 8 waves, 1 barrier/K-tile, read-ahead pipeline ----
// A: 2-slot ring (row-major XOR-swizzled); MODE0 gathers rows via etok, MODE1 linear hbuf.
// B: 3-slot ring (fragment-major pretile).
// XCD remap: mti-chunked per XCD, nt snake-fastest (A-page L2-resident per XCD).

#define MF(P, A0, A1, A2, A3)                                                                  \
  do {                                                                                         \
    __builtin_amdgcn_s_setprio(1);                                                             \
    _Pragma("unroll") for (int n = 0; n < 4; ++n)                                              \
        acc[2*(P)][n]   = __builtin_amdgcn_mfma_f32_16x16x32_bf16(A0, bg0[n], acc[2*(P)][n], 0, 0, 0); \
    _Pragma("unroll") for (int n = 0; n < 4; ++n)                                              \
        acc[2*(P)+1][n] = __builtin_amdgcn_mfma_f32_16x16x32_bf16(A2, bg0[n], acc[2*(P)+1][n], 0, 0, 0); \
    _Pragma("unroll") for (int n = 0; n < 4; ++n)                                              \
        acc[2*(P)][n]   = __builtin_amdgcn_mfma_f32_16x16x32_bf16(A1, bg1[n], acc[2*(P)][n], 0, 0, 0); \
    _Pragma("unroll") for (int n = 0; n < 4; ++n)                                              \
        acc[2*(P)+1][n] = __builtin_amdgcn_mfma_f32_16x16x32_bf16(A3, bg1[n], acc[2*(P)+1][n], 0, 0, 0); \
    __builtin_amdgcn_s_setprio(0);                                                             \
  } while (0)

template <int MODE>
__global__ __launch_bounds__(512, 2) void moe_gemm(
    const unsigned short* __restrict__ Abase,   // xb [TOKENS][DDIM] or hbuf [MAXENT][HC]
    const unsigned short* __restrict__ Bpre,
    const float* __restrict__ bias,
    const int* __restrict__ meta,
    const int* __restrict__ etok,
    const float* __restrict__ ewgt,
    unsigned short* __restrict__ Hbuf,
    float* __restrict__ Out,
    int Astride, int BtNT, int BtKT,
    int nbase, int kbase, int Klen,
    int biasStride, int Hstride, int addbias) {
  const int* offsets = meta + 16;
  int ntiles = meta[48];
  int NX = gridDim.x;
  int lid = blockIdx.x + NX * blockIdx.y;
  int Ntot = NX * ntiles;
  if (lid >= Ntot) return;
  int q = Ntot >> 3, r = Ntot & 7;
  int xcd = lid & 7, pos = lid >> 3;
  int nlid = (xcd < r ? xcd * (q + 1) : r * (q + 1) + (xcd - r) * q) + pos;
  int mti = nlid / NX;
  int rawnt = nlid - mti * NX;
  int nt = (mti & 1) ? (NX - 1 - rawnt) : rawnt;
  int te = meta[64 + mti];
  int e = te & 255, mt = te >> 8;
  int off = offsets[e], cnt = offsets[e + 1] - off;
  int total = offsets[NEXP];

  // A: [0,64K) 2 slots x 32 KiB. B: [64K,160K) 3 slots x 32 KiB.
  __shared__ __align__(128) char lds[163840];

  int tid = threadIdx.x;
  int lane = tid & 63, wid = tid >> 6;
  int wr = wid >> 2, wc = wid & 3;
  int fr = lane & 15, fu = lane >> 4;
  int cu0 = fu ^ (fr & 7);

  // ---- A staging sources (pre-swizzled source unit) ----
  int rg = (lane >> 3) & 7;
  int g = (lane & 7) ^ rg;
  const char* srcA[2][2];
#pragma unroll
  for (int h = 0; h < 2; ++h) {
#pragma unroll
    for (int j = 0; j < 2; ++j) {
      int rA = wid * 16 + j * 8 + rg;
      int gi = off + mt * 256 + h * 128 + rA;
      if (MODE == 0) {
        if (gi > total - 1) gi = total - 1;
        srcA[h][j] = (const char*)(Abase + (size_t)etok[gi] * Astride) + g * 16;
      } else {
        if (gi > MAXENT - 1) gi = MAXENT - 1;
        srcA[h][j] = (const char*)(Abase + (size_t)gi * Astride) + g * 16;
      }
    }
  }
  // ---- B staging sources (pretile: linear per wave) ----
  const char* srcB[2][2];
  {
    const char* BpreE = (const char*)Bpre +
        ((((size_t)e * BtNT + (nbase >> 8) + nt) * BtKT + (kbase >> 6)) << 15);
#pragma unroll
    for (int h = 0; h < 2; ++h)
#pragma unroll
      for (int j = 0; j < 2; ++j)
        srcB[h][j] = BpreE + (h << 14) + ((j * 8 + wid) << 10) + (lane << 4);
  }

#define STA(Tn, h) do { \
    char* _d = lds + (((Tn) & 1) << 15) + ((h) << 14) + (wid << 11); \
    gload16(srcA[h][0] + ((size_t)(Tn) << 7), _d); \
    gload16(srcA[h][1] + ((size_t)(Tn) << 7), _d + 1024); } while (0)
#define STB(sl, Tn, h) do { \
    char* _d = lds + 65536 + ((sl) * 32768) + ((h) << 14) + (wid << 10); \
    gload16(srcB[h][0] + ((size_t)(Tn) << 15), _d); \
    gload16(srcB[h][1] + ((size_t)(Tn) << 15), _d + 8192); } while (0)

  f32x4 acc[8][4];
#pragma unroll
  for (int m = 0; m < 8; ++m)
#pragma unroll
    for (int n = 0; n < 4; ++n) acc[m][n] = (f32x4){0.f, 0.f, 0.f, 0.f};

  bf16x8 bg0[4], bg1[4];
  auto rdA = [&](int T, int p, bf16x8& x0, bf16x8& x1, bf16x8& x2, bf16x8& x3) {
    const char* b = lds + ((T & 1) << 15) + (wr << 14) + fr * 128;
    const char* p0 = b + cu0 * 16;
    const char* p1 = b + (cu0 ^ 4) * 16;
    x0 = *(const bf16x8*)(p0 + (2 * p) * 2048);
    x1 = *(const bf16x8*)(p1 + (2 * p) * 2048);
    x2 = *(const bf16x8*)(p0 + (2 * p + 1) * 2048);
    x3 = *(const bf16x8*)(p1 + (2 * p + 1) * 2048);
  };
  auto rdB = [&](int sl) {
    const char* pb = lds + 65536 + sl * 32768 + (wc << 13) + (lane << 4);
#pragma unroll
    for (int n = 0; n < 4; ++n) {
      bg0[n] = *(const bf16x8*)(pb + n * 2048);
      bg1[n] = *(const bf16x8*)(pb + n * 2048 + 1024);
    }
  };

  int nk = Klen >> 6;

  STA(0, 0); STA(0, 1);
  STB(0, 0, 0); STB(0, 0, 1);
  STB(1, 1, 0); STB(1, 1, 1);
  VMWAIT(4);
  bar();

  bf16x8 c0, c1, c2, c3, n0, n1, n2, n3;
  rdA(0, 0, c0, c1, c2, c3);
  rdB(0);

  int bs = 0;
  for (int T = 0; T < nk; ++T) {
    int s1 = (T + 1 < nk), s2 = (T + 2 < nk);
    rdA(T, 1, n0, n1, n2, n3);
    if (s1) STA(T + 1, 0);
    MF(0, c0, c1, c2, c3);
    rdA(T, 2, c0, c1, c2, c3);
    if (s1) STA(T + 1, 1);
    MF(1, n0, n1, n2, n3);
    rdA(T, 3, n0, n1, n2, n3);
    int bs2 = bs >= 1 ? bs - 1 : bs + 2;
    if (s2) { STB(bs2, T + 2, 0); STB(bs2, T + 2, 1); }
    MF(2, c0, c1, c2, c3);
    MF(3, n0, n1, n2, n3);
    if (s2) { VMWAIT(4); } else if (s1) { VMWAIT(0); }
    bar();
    int Tn = s1 ? T + 1 : T;
    int bsn = bs < 2 ? bs + 1 : 0;
    rdA(Tn, 0, c0, c1, c2, c3);
    rdB(s1 ? bsn : bs);
    bs = bsn;
  }
#undef STA
#undef STB

  int colb = nt * 256 + wc * 64;
  if (MODE == 0) {
#pragma unroll
    for (int m = 0; m < 8; ++m) {
#pragma unroll
      for (int r = 0; r < 4; ++r) {
        int row = wr * 128 + m * 16 + fu * 4 + r;
        int gm = mt * 256 + row;
        if (gm < cnt) {
          size_t hrow = (size_t)(off + gm) * Hstride;
#pragma unroll
          for (int n = 0; n < 4; ++n) {
            int col = colb + n * 16 + fr;
            float v = acc[m][n][r] + bias[e * biasStride + nbase + col];
            v = v / (1.f + __expf(-v));
            Hbuf[hrow + col] = f2bf(v);
          }
        }
      }
    }
  } else {
#pragma unroll
    for (int m = 0; m < 8; ++m) {
#pragma unroll
      for (int r = 0; r < 4; ++r) {
        int row = wr * 128 + m * 16 + fu * 4 + r;
        int gm = mt * 256 + row;
        if (gm < cnt) {
          int ent = off + gm;
          int tok = etok[ent];
          float wgt = ewgt[ent];
#pragma unroll
          for (int n = 0; n < 4; ++n) {
            int col = colb + n * 16 + fr;
            float v = acc[m][n][r];
            if (addbias) v += bias[e * biasStride + col];
            atomicAdd(Out + (size_t)tok * DDIM + col, v * wgt);
          }
        }
      }
    }
  }
}

// ---------------- host launch ----------------

extern "C" void kernel_launch(void* const* d_in, const int* in_sizes, int n_in,
                              void* d_out, int out_size, void* d_ws, size_t ws_size,
                              hipStream_t stream) {
  (void)in_sizes; (void)n_in;
  const float* x = (const float*)d_in[0];
  const int* eidx = (const int*)d_in[1];
  const float* ew = (const float*)d_in[2];
  const float* w1 = (const float*)d_in[3];
  const float* b1 = (const float*)d_in[4];
  const float* w2 = (const float*)d_in[5];
  const float* b2 = (const float*)d_in[6];
  float* out = (float*)d_out;

  char* w = (char*)d_ws;
  size_t o_meta = 0;
  size_t o_etok = 4096;
  size_t o_ewgt = o_etok + (size_t)MAXENT * 4;
  size_t o_xb   = o_ewgt + (size_t)MAXENT * 4;
  size_t o_w1t  = o_xb + (size_t)TOKENS * DDIM * 2;        // 16 MB
  size_t o_w2t  = o_w1t + (size_t)DDIM * HDIM * NEXP * 2;  // +64 MB
  size_t o_h    = o_w2t + (size_t)DDIM * HDIM * NEXP * 2;  // +64 MB

  int S = 1;
  while (S < 16) {
    size_t need = o_h + (size_t)MAXENT * (HDIM / S) * 2;
    if (need <= ws_size) break;
    S *= 2;
  }
  int HC = HDIM / S;

  int* meta = (int*)(w + o_meta);
  int* etok = (int*)(w + o_etok);
  float* ewgt = (float*)(w + o_ewgt);
  unsigned short* xb = (unsigned short*)(w + o_xb);
  unsigned short* w1t = (unsigned short*)(w + o_w1t);
  unsigned short* w2t = (unsigned short*)(w + o_w2t);
  unsigned short* hbuf = (unsigned short*)(w + o_h);

  hipMemsetAsync(d_out, 0, (size_t)out_size * 4, stream);

  prep_all<<<1, 1024, 0, stream>>>(eidx, ew, meta, etok, ewgt);
  cvt_x_bf16<<<(TOKENS * DDIM / 8 + 255) / 256, 256, 0, stream>>>(x, xb, TOKENS * DDIM / 8);
  pretile_both<<<NEXP * (HDIM >> 8) * (DDIM >> 6) + NEXP * (DDIM >> 8) * (HDIM >> 6),
                 256, 0, stream>>>(w1, w2, w1t, w2t);

  for (int s = 0; s < S; ++s) {
    moe_gemm<0><<<dim3(HC / 256, MAXTILES, 1), 512, 0, stream>>>(
        xb, w1t, b1, meta, etok, ewgt, hbuf, nullptr,
        DDIM, HDIM / 256, DDIM / 64, s * HC, 0, DDIM, HDIM, HC, 0);
    moe_gemm<1><<<dim3(DDIM / 256, MAXTILES, 1), 512, 0, stream>>>(
        hbuf, w2t, b2, meta, etok, ewgt, nullptr, out,
        HC, DDIM / 256, HDIM / 64, 0, s * HC, HC, DDIM, 0, (s == 0) ? 1 : 0);
  }
}